// Round 1
// baseline (1134.311 us; speedup 1.0000x reference)
//
#include <hip/hip_runtime.h>
#include <hip/hip_bf16.h>

// Problem constants
#define NATOM   100000
#define MNBR    12
#define RTOT    1200000      // NATOM*MNBR rows
#define AF      64
#define BF      41
#define KF      169          // 2*AF + BF
#define KP      192          // padded K for 6 chunks of 32
#define KPAD    200          // LDS row stride (bf16 elems) - 2-way bank conflict only
#define CO      128          // output cols of GEMM
#define NBLK1   18750        // RTOT / 64
#define NBLK3   25000        // NATOM / 4

typedef short bf16x8 __attribute__((ext_vector_type(8)));
typedef float f32x4  __attribute__((ext_vector_type(4)));

static __device__ __forceinline__ unsigned short f2bf(float x) {
    unsigned int u = __builtin_bit_cast(unsigned int, x);
    u = u + 0x7FFFu + ((u >> 16) & 1u);   // RNE
    return (unsigned short)(u >> 16);
}
static __device__ __forceinline__ float bf2f(unsigned short h) {
    unsigned int u = ((unsigned int)h) << 16;
    return __builtin_bit_cast(float, u);
}
static __device__ __forceinline__ float softplus_f(float x) {
    return fmaxf(x, 0.0f) + log1pf(__expf(-fabsf(x)));
}

// ---------------- kernel 0: pre-convert W to bf16, [col][k] padded ----------
__global__ __launch_bounds__(256) void k0_prep(const float* __restrict__ W,
                                               unsigned short* __restrict__ Wbf) {
    int i = blockIdx.x * 256 + threadIdx.x;     // < 128*KPAD = 25600
    if (i >= CO * KPAD) return;
    int c = i / KPAD;
    int k = i - c * KPAD;
    unsigned short v = 0;
    if (k < KF) v = f2bf(W[k * CO + c]);
    Wbf[i] = v;
}

// ---------------- kernel 1: gather+concat + GEMM + bias + BN1 partials ------
__global__ __launch_bounds__(256) void k1_gemm(
    const int*   __restrict__ idx,     // (N, 12)
    const float* __restrict__ atom,    // (N, 64)
    const float* __restrict__ bond,    // (N, 12, 41)
    const unsigned short* __restrict__ Wbf,  // (128, KPAD) bf16 padded
    const float* __restrict__ bias,    // (128,)
    unsigned short* __restrict__ gated,      // (RTOT, 128) bf16 out
    float* __restrict__ part1)               // (256, NBLK1): rows 0..127 sum, 128..255 sumsq
{
    __shared__ __align__(16) unsigned short Wl[CO * KPAD];   // 51200 B
    __shared__ __align__(16) unsigned short Al[64 * KPAD];   // 25600 B
    __shared__ float pS[128], pQ[128];

    const int tid = threadIdx.x;
    const int blk = blockIdx.x;

    if (tid < 128) { pS[tid] = 0.0f; pQ[tid] = 0.0f; }

    // copy pre-converted W (includes zero pads) into LDS
    {
        const uint4* src = (const uint4*)Wbf;
        uint4* dst = (uint4*)Wl;
        #pragma unroll
        for (int i = tid; i < CO * KPAD * 2 / 16; i += 256) dst[i] = src[i];
    }
    // zero A tile (covers k >= 169 padding)
    {
        unsigned int* az = (unsigned int*)Al;
        for (int i = tid; i < 64 * KPAD / 2; i += 256) az[i] = 0u;
    }
    __syncthreads();

    // stage A: 64 rows, 4 threads per row for self/nbr
    {
        int r = tid >> 2;          // 0..63
        int q = tid & 3;
        int row = blk * 64 + r;
        int n = row / MNBR;
        int m = row - n * MNBR;
        int nb = idx[n * MNBR + m];
        const float4* selfp = (const float4*)(atom + (size_t)n  * AF);
        const float4* nbrp  = (const float4*)(atom + (size_t)nb * AF);
        #pragma unroll
        for (int j = q; j < 16; j += 4) {
            float4 v = selfp[j];
            ushort4 w; w.x = f2bf(v.x); w.y = f2bf(v.y); w.z = f2bf(v.z); w.w = f2bf(v.w);
            *(ushort4*)&Al[r * KPAD + j * 4] = w;
            float4 u = nbrp[j];
            ushort4 w2; w2.x = f2bf(u.x); w2.y = f2bf(u.y); w2.z = f2bf(u.z); w2.w = f2bf(u.w);
            *(ushort4*)&Al[r * KPAD + AF + j * 4] = w2;
        }
    }
    // stage bond: block's 64 rows are contiguous: 64*41 = 2624 floats
    {
        const float* bblk = bond + (size_t)blk * (64 * BF);
        for (int j = tid; j < 64 * BF; j += 256) {
            float v = bblk[j];
            int rr = j / BF;
            int kk = j - rr * BF;
            Al[rr * KPAD + 2 * AF + kk] = f2bf(v);
        }
    }
    __syncthreads();

    // MFMA: wave w handles rows [w*16, w*16+16), all 128 cols
    const int wv  = tid >> 6;
    const int ln  = tid & 63;
    const int l15 = ln & 15;
    const int kq  = ln >> 4;          // 0..3
    const int arow = wv * 16 + l15;

    bf16x8 afr[6];
    #pragma unroll
    for (int kc = 0; kc < 6; ++kc)
        afr[kc] = *(const bf16x8*)&Al[arow * KPAD + kc * 32 + kq * 8];

    f32x4 acc[8];
    #pragma unroll
    for (int ct = 0; ct < 8; ++ct) {
        f32x4 a = {0.f, 0.f, 0.f, 0.f};
        #pragma unroll
        for (int kc = 0; kc < 6; ++kc) {
            bf16x8 bfr = *(const bf16x8*)&Wl[(ct * 16 + l15) * KPAD + kc * 32 + kq * 8];
            a = __builtin_amdgcn_mfma_f32_16x16x32_bf16(afr[kc], bfr, a, 0, 0, 0);
        }
        acc[ct] = a;
    }

    // epilogue: bias, store bf16, per-block BN1 partial stats
    const int rbase = wv * 16 + kq * 4;
    #pragma unroll
    for (int ct = 0; ct < 8; ++ct) {
        int col = ct * 16 + l15;
        float bv = bias[col];
        float s = 0.f, qq = 0.f;
        #pragma unroll
        for (int rg = 0; rg < 4; ++rg) {
            float v = acc[ct][rg] + bv;
            size_t grow = (size_t)blk * 64 + rbase + rg;
            gated[grow * CO + col] = f2bf(v);
            s += v; qq += v * v;
        }
        s  += __shfl_xor(s, 16);  s  += __shfl_xor(s, 32);
        qq += __shfl_xor(qq, 16); qq += __shfl_xor(qq, 32);
        if (kq == 0) { atomicAdd(&pS[col], s); atomicAdd(&pQ[col], qq); }
    }
    __syncthreads();
    if (tid < 128) {
        part1[(size_t)tid        * NBLK1 + blk] = pS[tid];
        part1[(size_t)(128 + tid)* NBLK1 + blk] = pQ[tid];
    }
}

// ---------------- kernel 2: finalize BN1 stats -> g1,h1 ---------------------
__global__ __launch_bounds__(256) void k2_stats1(const float* __restrict__ part1,
                                                 const float* __restrict__ scale,
                                                 const float* __restrict__ offset,
                                                 float* __restrict__ stats1) {
    int c = blockIdx.x;            // 0..127
    int t = threadIdx.x;
    const float* ps = part1 + (size_t)c * NBLK1;
    const float* pq = part1 + (size_t)(128 + c) * NBLK1;
    float s = 0.f, q = 0.f;
    for (int i = t; i < NBLK1; i += 256) { s += ps[i]; q += pq[i]; }
    __shared__ float rs[256], rq[256];
    rs[t] = s; rq[t] = q;
    __syncthreads();
    for (int o = 128; o > 0; o >>= 1) {
        if (t < o) { rs[t] += rs[t + o]; rq[t] += rq[t + o]; }
        __syncthreads();
    }
    if (t == 0) {
        const float inv = 1.0f / (float)RTOT;
        float mean = rs[0] * inv;
        float var  = rq[0] * inv - mean * mean;
        float g = scale[c] * rsqrtf(var + 1e-5f);
        float h = offset[c] - mean * g;
        stats1[c] = g; stats1[128 + c] = h;
    }
}

// ------- kernel 3: BN1-apply + sigmoid*softplus + sum over M + BN2 partials -
__global__ __launch_bounds__(256) void k3_act(const unsigned short* __restrict__ gated,
                                              const float* __restrict__ stats1,
                                              float* __restrict__ summed,
                                              float* __restrict__ part2) {
    int t  = threadIdx.x;
    int al = t >> 6;          // 0..3 (atom within block)
    int c  = t & 63;
    int n  = blockIdx.x * 4 + al;
    float gf = stats1[c],      hf = stats1[128 + c];
    float gc = stats1[64 + c], hc = stats1[192 + c];
    const unsigned short* gp = gated + (size_t)n * MNBR * CO;
    float acc = 0.f;
    #pragma unroll
    for (int m = 0; m < MNBR; ++m) {
        float xf = bf2f(gp[m * CO + c]);
        float xc = bf2f(gp[m * CO + 64 + c]);
        float yf = gf * xf + hf;
        float yc = gc * xc + hc;
        float sig = 1.0f / (1.0f + __expf(-yf));
        acc += sig * softplus_f(yc);
    }
    summed[(size_t)n * 64 + c] = acc;
    __shared__ float sA[256], sB[256];
    sA[t] = acc; sB[t] = acc * acc;
    __syncthreads();
    if (t < 64) {
        float s = sA[t] + sA[t + 64] + sA[t + 128] + sA[t + 192];
        float q = sB[t] + sB[t + 64] + sB[t + 128] + sB[t + 192];
        part2[(size_t)t        * NBLK3 + blockIdx.x] = s;
        part2[(size_t)(64 + t) * NBLK3 + blockIdx.x] = q;
    }
}

// ---------------- kernel 4: finalize BN2 stats -> g2,h2 ---------------------
__global__ __launch_bounds__(256) void k4_stats2(const float* __restrict__ part2,
                                                 const float* __restrict__ scale,
                                                 const float* __restrict__ offset,
                                                 float* __restrict__ stats2) {
    int c = blockIdx.x;            // 0..63
    int t = threadIdx.x;
    const float* ps = part2 + (size_t)c * NBLK3;
    const float* pq = part2 + (size_t)(64 + c) * NBLK3;
    float s = 0.f, q = 0.f;
    for (int i = t; i < NBLK3; i += 256) { s += ps[i]; q += pq[i]; }
    __shared__ float rs[256], rq[256];
    rs[t] = s; rq[t] = q;
    __syncthreads();
    for (int o = 128; o > 0; o >>= 1) {
        if (t < o) { rs[t] += rs[t + o]; rq[t] += rq[t + o]; }
        __syncthreads();
    }
    if (t == 0) {
        const float inv = 1.0f / (float)NATOM;
        float mean = rs[0] * inv;
        float var  = rq[0] * inv - mean * mean;
        float g = scale[c] * rsqrtf(var + 1e-5f);
        float h = offset[c] - mean * g;
        stats2[c] = g; stats2[64 + c] = h;
    }
}

// ---------------- kernel 5: out = softplus(atom + BN2(summed)) --------------
__global__ __launch_bounds__(256) void k5_out(const float* __restrict__ atom,
                                              const float* __restrict__ summed,
                                              const float* __restrict__ stats2,
                                              float* __restrict__ out) {
    int i = blockIdx.x * 256 + threadIdx.x;   // < NATOM*64
    int c = i & 63;
    float g = stats2[c], h = stats2[64 + c];
    float v = atom[i] + g * summed[i] + h;
    out[i] = softplus_f(v);
}

extern "C" void kernel_launch(void* const* d_in, const int* in_sizes, int n_in,
                              void* d_out, int out_size, void* d_ws, size_t ws_size,
                              hipStream_t stream) {
    const int*   idx  = (const int*)  d_in[0];
    const float* atom = (const float*)d_in[1];
    const float* bond = (const float*)d_in[2];
    const float* W    = (const float*)d_in[3];
    const float* bias = (const float*)d_in[4];
    const float* bn1s = (const float*)d_in[5];
    const float* bn1o = (const float*)d_in[6];
    const float* bn2s = (const float*)d_in[7];
    const float* bn2o = (const float*)d_in[8];
    float* out = (float*)d_out;

    char* ws = (char*)d_ws;
    size_t off = 0;
    unsigned short* Wbf   = (unsigned short*)(ws + off); off += (size_t)CO * KPAD * 2;      // 51,200
    unsigned short* gated = (unsigned short*)(ws + off); off += (size_t)RTOT * CO * 2;      // 307,200,000
    float* part1  = (float*)(ws + off); off += (size_t)256 * NBLK1 * 4;                     // 19,200,000
    float* stats1 = (float*)(ws + off); off += 256 * 4;
    float* summed = (float*)(ws + off); off += (size_t)NATOM * 64 * 4;                      // 25,600,000
    float* part2  = (float*)(ws + off); off += (size_t)128 * NBLK3 * 4;                     // 12,800,000
    float* stats2 = (float*)(ws + off); off += 128 * 4;

    k0_prep  <<<(CO * KPAD + 255) / 256, 256, 0, stream>>>(W, Wbf);
    k1_gemm  <<<NBLK1, 256, 0, stream>>>(idx, atom, bond, Wbf, bias, gated, part1);
    k2_stats1<<<128, 256, 0, stream>>>(part1, bn1s, bn1o, stats1);
    k3_act   <<<NBLK3, 256, 0, stream>>>(gated, stats1, summed, part2);
    k4_stats2<<<64, 256, 0, stream>>>(part2, bn2s, bn2o, stats2);
    k5_out   <<<(NATOM * 64 + 255) / 256, 256, 0, stream>>>(atom, summed, stats2, out);
}

// Round 3
// 584.689 us; speedup vs baseline: 1.9400x; 1.9400x over previous
//
#include <hip/hip_runtime.h>

#define NATOM 100000
#define MNBR  12
#define RTOT  1200000
#define KF    169
#define NT    25000      // tiles of 48 rows (= 4 atoms)
#define NBP   1024       // blocks per pass kernel
#define EPS   1e-5f

typedef short  bf16x8 __attribute__((ext_vector_type(8)));
typedef float  f32x4  __attribute__((ext_vector_type(4)));
typedef unsigned short us8 __attribute__((ext_vector_type(8)));

static __device__ __forceinline__ unsigned short f2bf(float x) {
    unsigned int u = __builtin_bit_cast(unsigned int, x);
    u = u + 0x7FFFu + ((u >> 16) & 1u);   // RNE
    return (unsigned short)(u >> 16);
}
static __device__ __forceinline__ float softplus_f(float x) {
    return fmaxf(x, 0.f) + __logf(1.f + __expf(-fabsf(x)));
}
__device__ __forceinline__ void gload16(const void* g, void* l) {
    __builtin_amdgcn_global_load_lds((const __attribute__((address_space(1))) void*)g,
                                     (__attribute__((address_space(3))) void*)l, 16, 0, 0);
}
#define FENCE() asm volatile("" ::: "memory")

// ---------- k0: convert bond -> bf16 [RTOT][48] (zero pad), atom -> bf16, W -> bf16 [128][192]^T
__global__ __launch_bounds__(256) void k0conv(const float* __restrict__ bond,
                                              const float* __restrict__ atom,
                                              const float* __restrict__ W,
                                              unsigned short* __restrict__ bondbf,
                                              unsigned short* __restrict__ atombf,
                                              unsigned short* __restrict__ Wbf) {
    int b = blockIdx.x;
    if (b < 28125) {                       // bond: 57.6M out elems, 8 per thread
        int j0 = (b * 256 + (int)threadIdx.x) * 8;
        int r  = j0 / 48;
        int q  = j0 - r * 48;              // 0,8,16,24,32,40
        us8 o;
        #pragma unroll
        for (int e = 0; e < 8; ++e) {
            int c = q + e;
            float v = (c < 41) ? bond[(size_t)r * 41 + c] : 0.f;
            o[e] = f2bf(v);
        }
        *(us8*)(bondbf + j0) = o;
    } else if (b < 31250) {                // atom: 6.4M elems, 8 per thread
        int i8 = ((b - 28125) * 256 + (int)threadIdx.x) * 8;
        float4 v0 = *(const float4*)(atom + i8);
        float4 v1 = *(const float4*)(atom + i8 + 4);
        us8 o;
        o[0]=f2bf(v0.x); o[1]=f2bf(v0.y); o[2]=f2bf(v0.z); o[3]=f2bf(v0.w);
        o[4]=f2bf(v1.x); o[5]=f2bf(v1.y); o[6]=f2bf(v1.z); o[7]=f2bf(v1.w);
        *(us8*)(atombf + i8) = o;
    } else {                               // W: [col][k] k-padded to 192, 24576 elems
        int i = (b - 31250) * 256 + (int)threadIdx.x;
        if (i < 128 * 192) {
            int c = i / 192, k = i - c * 192;
            Wbf[i] = (k < KF) ? f2bf(W[k * 128 + c]) : (unsigned short)0;
        }
    }
}

// ---------- generic BN stats finalize: g = scale*rsqrt(var+eps), h = offset - mean*g
__global__ __launch_bounds__(256) void k_stats(const float* __restrict__ part,
                                               const float* __restrict__ scale,
                                               const float* __restrict__ offset,
                                               float* __restrict__ stats,
                                               int ncols, float invR) {
    int c = blockIdx.x, t = threadIdx.x;
    const float* ps = part + (size_t)c * NBP;
    const float* pq = part + (size_t)(ncols + c) * NBP;
    float s = 0.f, q = 0.f;
    for (int i = t; i < NBP; i += 256) { s += ps[i]; q += pq[i]; }
    __shared__ float rs[256], rq[256];
    rs[t] = s; rq[t] = q;
    __syncthreads();
    for (int o = 128; o > 0; o >>= 1) {
        if (t < o) { rs[t] += rs[t + o]; rq[t] += rq[t + o]; }
        __syncthreads();
    }
    if (t == 0) {
        float mean = rs[0] * invR;
        float var  = rq[0] * invR - mean * mean;
        float g = scale[c] * rsqrtf(var + EPS);
        stats[c] = g;
        stats[ncols + c] = offset[c] - mean * g;
    }
}

// ---------- fused GEMM pass. PASS=1: BN1 partial stats. PASS=2: BN1-apply+act+m-sum+BN2 partials.
// Tile = 48 rows (4 atoms). Waves: wave w holds W-frags for cols {w*16+l15, 64+w*16+l15}.
// LDS panels per buffer: self[48][128B] (XOR-swizzled), nbr same, bond[48][96B]+pad (linear).
template<int PASS>
__global__ __launch_bounds__(256, 4) void kpass(const int* __restrict__ idx,
                                                const unsigned short* __restrict__ atombf,
                                                const unsigned short* __restrict__ bondbf,
                                                const unsigned short* __restrict__ Wbf,
                                                const float* __restrict__ stats1,
                                                float* __restrict__ part,
                                                float* __restrict__ summed) {
    __shared__ unsigned short AB[2][8704];   // 2 x (3072 self + 3072 nbr + 2560 bond) ushorts
    __shared__ float sm[256];

    const int tid = threadIdx.x;
    const int wv  = tid >> 6;
    const int ln  = tid & 63;
    const int l15 = ln & 15;
    const int kq  = ln >> 4;
    const int blk = blockIdx.x;
    const int cf  = wv * 16 + l15;           // filter col (0..63)

    // --- W fragments in registers (held across whole kernel)
    bf16x8 wfr[2][6];
    #pragma unroll
    for (int h = 0; h < 2; ++h) {
        int col = cf + h * 64;
        #pragma unroll
        for (int kc = 0; kc < 6; ++kc)
            wfr[h][kc] = *(const bf16x8*)((const char*)Wbf + col * 384 + kc * 64 + kq * 16);
    }
    float gf=0.f, hf=0.f, gc=0.f, hc=0.f;
    if (PASS == 2) {
        gf = stats1[cf];       hf = stats1[128 + cf];
        gc = stats1[64 + cf];  hc = stats1[192 + cf];
        sm[tid] = 0.f;
    }
    float s0 = 0.f, q0 = 0.f, s1 = 0.f, q1 = 0.f;

    int idxreg[4];
    // prefetch idx values for this wave's nbr staging insts of tile t
    auto PREFIDX = [&](int t) {
        #pragma unroll
        for (int j = 0; j < 4; ++j) {
            int i = wv * 4 + j;
            if (i >= 6 && i < 12) {
                int o = (i - 6) * 1024 + ln * 16;
                idxreg[j] = idx[t * 48 + (o >> 7)];
            }
        }
    };
    // issue this wave's staging loads for tile t into buffer bsel
    auto STAGE = [&](int t, int bsel) {
        unsigned short* buf = &AB[bsel][0];
        #pragma unroll
        for (int j = 0; j < 4; ++j) {
            int i = wv * 4 + j;
            if (i < 6) {                       // self panel, swizzled source
                int o  = i * 1024 + ln * 16;
                int os = o ^ (((o >> 7) & 7) << 4);
                int row = o >> 7;
                int n = (t * 48 + row) / 12;
                gload16(atombf + n * 64 + ((os & 127) >> 1), buf + (o >> 1));
            } else if (i < 12) {               // nbr panel
                int o  = (i - 6) * 1024 + ln * 16;
                int os = o ^ (((o >> 7) & 7) << 4);
                int n = idxreg[j];
                gload16(atombf + n * 64 + ((os & 127) >> 1), buf + 3072 + (o >> 1));
            } else {                           // bond panel, linear copy
                int o = (i - 12) * 1024 + ln * 16;
                gload16(bondbf + (size_t)t * 2304 + (o >> 1), buf + 6144 + (o >> 1));
            }
        }
        if (wv == 0) {                          // inst 16: bond tail (incl. 512B over-read, slack-covered)
            int o = 4 * 1024 + ln * 16;
            gload16(bondbf + (size_t)t * 2304 + (o >> 1), buf + 6144 + (o >> 1));
        }
    };

    int t0 = blk;
    PREFIDX(t0);
    asm volatile("s_waitcnt vmcnt(0)" ::: "memory");   // drain W/stats/idx before counted discipline
    STAGE(t0, 0);
    if (t0 + NBP < NT) PREFIDX(t0 + NBP);

    int b = 0;
    for (int t = t0; t < NT; t += NBP) {
        bool hn = (t + NBP) < NT;
        if (PASS == 2) asm volatile("s_waitcnt lgkmcnt(0)" ::: "memory");
        __builtin_amdgcn_s_barrier();           // (A) everyone done with buf b^1
        FENCE();
        if (hn) STAGE(t + NBP, b ^ 1);
        if (hn) {
            if (wv == 0) asm volatile("s_waitcnt vmcnt(5)" ::: "memory");
            else         asm volatile("s_waitcnt vmcnt(4)" ::: "memory");
        } else {
            asm volatile("s_waitcnt vmcnt(0)" ::: "memory");
        }
        __builtin_amdgcn_s_barrier();           // (B) buf b fully staged (all waves)
        FENCE();

        const unsigned short* buf = &AB[b][0];
        f32x4 z = {0.f, 0.f, 0.f, 0.f};
        f32x4 acc[2][3];
        #pragma unroll
        for (int s = 0; s < 3; ++s) { acc[0][s] = z; acc[1][s] = z; }

        #pragma unroll
        for (int sub = 0; sub < 3; ++sub) {
            int row = sub * 16 + l15;
            #pragma unroll
            for (int kc = 0; kc < 6; ++kc) {
                const char* p;
                if (kc < 2)
                    p = (const char*)buf + ((row * 128 + kc * 64 + kq * 16) ^ ((row & 7) << 4));
                else if (kc < 4)
                    p = (const char*)(buf + 3072) + ((row * 128 + (kc - 2) * 64 + kq * 16) ^ ((row & 7) << 4));
                else
                    p = (const char*)(buf + 6144) + (row * 96 + (kc - 4) * 64 + kq * 16);
                bf16x8 a = *(const bf16x8*)p;
                acc[0][sub] = __builtin_amdgcn_mfma_f32_16x16x32_bf16(a, wfr[0][kc], acc[0][sub], 0, 0, 0);
                acc[1][sub] = __builtin_amdgcn_mfma_f32_16x16x32_bf16(a, wfr[1][kc], acc[1][sub], 0, 0, 0);
            }
        }

        if (PASS == 1) {
            #pragma unroll
            for (int sub = 0; sub < 3; ++sub)
                #pragma unroll
                for (int rg = 0; rg < 4; ++rg) {
                    float v0 = acc[0][sub][rg]; s0 += v0; q0 = fmaf(v0, v0, q0);
                    float v1 = acc[1][sub][rg]; s1 += v1; q1 = fmaf(v1, v1, q1);
                }
        } else {
            #pragma unroll
            for (int sub = 0; sub < 3; ++sub) {
                float ps = 0.f;
                #pragma unroll
                for (int rg = 0; rg < 4; ++rg) {
                    float yf = fmaf(acc[0][sub][rg], gf, hf);
                    float yc = fmaf(acc[1][sub][rg], gc, hc);
                    float sig = __builtin_amdgcn_rcpf(1.f + __expf(-yf));
                    ps = fmaf(sig, softplus_f(yc), ps);
                }
                int a = (sub * 16 + kq * 4) / 12;      // quad never straddles an atom
                atomicAdd(&sm[a * 64 + cf], ps);
            }
            asm volatile("s_waitcnt lgkmcnt(0)" ::: "memory");
            __builtin_amdgcn_s_barrier();       // (C) all atomics for this tile done
            FENCE();
            float v = sm[tid];
            sm[tid] = 0.f;
            summed[(size_t)t * 256 + tid] = v;   // [atom][col], coalesced
            s0 += v; q0 = fmaf(v, v, q0);
        }
        b ^= 1;
        if (t + 2 * NBP < NT) PREFIDX(t + 2 * NBP);
    }

    // --- write partial stats
    if (PASS == 1) {
        s0 += __shfl_xor(s0, 16); s0 += __shfl_xor(s0, 32);
        q0 += __shfl_xor(q0, 16); q0 += __shfl_xor(q0, 32);
        s1 += __shfl_xor(s1, 16); s1 += __shfl_xor(s1, 32);
        q1 += __shfl_xor(q1, 16); q1 += __shfl_xor(q1, 32);
        if (ln < 16) {
            part[(size_t)cf * NBP + blk]          = s0;
            part[(size_t)(128 + cf) * NBP + blk]  = q0;
            part[(size_t)(64 + cf) * NBP + blk]   = s1;
            part[(size_t)(192 + cf) * NBP + blk]  = q1;
        }
    } else {
        __syncthreads();
        float* fs = (float*)&AB[0][0];
        fs[tid] = s0; fs[256 + tid] = q0;
        __syncthreads();
        if (tid < 64) {
            float S = fs[tid] + fs[tid + 64] + fs[tid + 128] + fs[tid + 192];
            float Q = fs[256 + tid] + fs[256 + tid + 64] + fs[256 + tid + 128] + fs[256 + tid + 192];
            part[(size_t)tid * NBP + blk]        = S;
            part[(size_t)(64 + tid) * NBP + blk] = Q;
        }
    }
}

// ---------- k5: out = softplus(atom + g2*summed + h2)
__global__ __launch_bounds__(256) void k5_out(const float* __restrict__ atom,
                                              const float* __restrict__ summed,
                                              const float* __restrict__ stats2,
                                              float* __restrict__ out) {
    int i4 = blockIdx.x * 256 + threadIdx.x;
    int base = i4 * 4;
    int c = base & 63;
    float4 av = *(const float4*)(atom + base);
    float4 sv = *(const float4*)(summed + base);
    float4 ov;
    ov.x = softplus_f(av.x + stats2[c + 0] * sv.x + stats2[64 + c + 0]);
    ov.y = softplus_f(av.y + stats2[c + 1] * sv.y + stats2[64 + c + 1]);
    ov.z = softplus_f(av.z + stats2[c + 2] * sv.z + stats2[64 + c + 2]);
    ov.w = softplus_f(av.w + stats2[c + 3] * sv.w + stats2[64 + c + 3]);
    *(float4*)(out + base) = ov;
}

extern "C" void kernel_launch(void* const* d_in, const int* in_sizes, int n_in,
                              void* d_out, int out_size, void* d_ws, size_t ws_size,
                              hipStream_t stream) {
    const int*   idx  = (const int*)  d_in[0];
    const float* atom = (const float*)d_in[1];
    const float* bond = (const float*)d_in[2];
    const float* W    = (const float*)d_in[3];
    // d_in[4] = bias: absorbed by BN1, unused
    const float* bn1s = (const float*)d_in[5];
    const float* bn1o = (const float*)d_in[6];
    const float* bn2s = (const float*)d_in[7];
    const float* bn2o = (const float*)d_in[8];
    float* out = (float*)d_out;

    char* ws = (char*)d_ws;
    size_t off = 0;
    unsigned short* atombf = (unsigned short*)(ws + off); off += 12800000;           // [N][64] bf16
    unsigned short* bondbf = (unsigned short*)(ws + off); off += 115201024;          // [RTOT][48] bf16 + 1KB slack
    unsigned short* Wbf    = (unsigned short*)(ws + off); off += 49152;              // [128][192] bf16
    float* part1  = (float*)(ws + off); off += 256 * NBP * 4;                        // 1 MB
    float* stats1 = (float*)(ws + off); off += 1024;
    float* part2  = (float*)(ws + off); off += 128 * NBP * 4;                        // 512 KB
    float* stats2 = (float*)(ws + off); off += 512;
    float* summed = (float*)(ws + off); off += 25600000;

    k0conv <<<31346, 256, 0, stream>>>(bond, atom, W, bondbf, atombf, Wbf);
    kpass<1><<<NBP, 256, 0, stream>>>(idx, atombf, bondbf, Wbf, stats1, part1, summed);
    k_stats<<<128, 256, 0, stream>>>(part1, bn1s, bn1o, stats1, 128, 1.f / (float)RTOT);
    kpass<2><<<NBP, 256, 0, stream>>>(idx, atombf, bondbf, Wbf, stats1, part2, summed);
    k_stats<<<64, 256, 0, stream>>>(part2, bn2s, bn2o, stats2, 64, 1.f / (float)NATOM);
    k5_out <<<6250, 256, 0, stream>>>(atom, summed, stats2, out);
}

// Round 6
// 549.256 us; speedup vs baseline: 2.0652x; 1.0645x over previous
//
#include <hip/hip_runtime.h>

#define NATOM 100000
#define MNBR  12
#define RTOT  1200000
#define KF    169
#define NT    12500          // tiles of 96 rows (= 8 atoms)
#define NBP   512            // blocks per pass kernel (2 per CU)
#define IDXB  4800000        // idx bytes
#define EPS   1e-5f

// LDS region offsets within one buffer (bytes):
//   nbr   @ 0      size 12288 (XOR-swizzled)
//   bond  @ 12288  size 9216
//   pad   @ 21504  size 128   (ZEROED once; absorbs bond chunk-5 over-read at rowa=95)
//   spre  @ 21632  size 4096  (fp32)
//   idx   @ 25728  size 1024
#define LBSZ  26752

typedef short  bf16x8 __attribute__((ext_vector_type(8)));
typedef float  f32x4  __attribute__((ext_vector_type(4)));
typedef unsigned short us8 __attribute__((ext_vector_type(8)));

static __device__ __forceinline__ unsigned short f2bf(float x) {
    unsigned int u = __builtin_bit_cast(unsigned int, x);
    u = u + 0x7FFFu + ((u >> 16) & 1u);   // RNE
    return (unsigned short)(u >> 16);
}
static __device__ __forceinline__ float softplus_f(float x) {
    return fmaxf(x, 0.f) + __logf(1.f + __expf(-fabsf(x)));
}
__device__ __forceinline__ void gload16(const void* g, void* l) {
    __builtin_amdgcn_global_load_lds((const __attribute__((address_space(1))) void*)g,
                                     (__attribute__((address_space(3))) void*)l, 16, 0, 0);
}
#define FENCE() asm volatile("" ::: "memory")

// ---------- k0: bond -> bf16 [RTOT][48] (zero pad, LDS repack), atom -> bf16, W -> bf16 [col][192]
__global__ __launch_bounds__(256) void k0conv(const float* __restrict__ bond,
                                              const float* __restrict__ atom,
                                              const float* __restrict__ W,
                                              unsigned short* __restrict__ bondbf,
                                              unsigned short* __restrict__ atombf,
                                              unsigned short* __restrict__ Wbf) {
    int b = blockIdx.x;
    if (b < 9375) {                        // bond: 128 rows per block
        __shared__ float Lf[5248];         // 128*41
        const float* src = bond + (size_t)b * 5248;
        for (int i = threadIdx.x; i < 5248; i += 256) Lf[i] = src[i];
        __syncthreads();
        unsigned short* dst = bondbf + (size_t)b * 6144;
        for (int cc = threadIdx.x; cc < 768; cc += 256) {   // 768 chunks of 8
            int row = cc / 6;
            int cs  = (cc - row * 6) * 8;
            us8 o;
            #pragma unroll
            for (int e = 0; e < 8; ++e) {
                int col = cs + e;
                o[e] = (col < 41) ? f2bf(Lf[row * 41 + col]) : (unsigned short)0;
            }
            *(us8*)(dst + cc * 8) = o;
        }
    } else if (b < 9375 + 3125) {          // atom: 6.4M elems, 8 per thread
        int i8 = ((b - 9375) * 256 + (int)threadIdx.x) * 8;
        float4 v0 = *(const float4*)(atom + i8);
        float4 v1 = *(const float4*)(atom + i8 + 4);
        us8 o;
        o[0]=f2bf(v0.x); o[1]=f2bf(v0.y); o[2]=f2bf(v0.z); o[3]=f2bf(v0.w);
        o[4]=f2bf(v1.x); o[5]=f2bf(v1.y); o[6]=f2bf(v1.z); o[7]=f2bf(v1.w);
        *(us8*)(atombf + i8) = o;
    } else {                               // W: [col][k] padded K->192
        int i = (b - 12500) * 256 + (int)threadIdx.x;
        if (i < 128 * 192) {
            int c = i / 192, k = i - c * 192;
            Wbf[i] = (k < KF) ? f2bf(W[k * 128 + c]) : (unsigned short)0;
        }
    }
}

// ---------- k0b: Spre[n][c] = self(n) . Wself(c)   (fp32 out)
__global__ __launch_bounds__(256) void k0spre(const unsigned short* __restrict__ atombf,
                                              const unsigned short* __restrict__ Wbf,
                                              float* __restrict__ Spre) {
    int blk = blockIdx.x;
    int tid = threadIdx.x, wv = tid >> 6, ln = tid & 63, l15 = ln & 15, kq = ln >> 4;
    int rowa = blk * 64 + wv * 16 + l15;
    int rla  = rowa < NATOM ? rowa : NATOM - 1;
    bf16x8 af0 = *(const bf16x8*)(atombf + (size_t)rla * 64 + kq * 8);
    bf16x8 af1 = *(const bf16x8*)(atombf + (size_t)rla * 64 + 32 + kq * 8);
    int rowo = blk * 64 + wv * 16 + kq * 4;
    #pragma unroll
    for (int ct = 0; ct < 8; ++ct) {
        f32x4 a = {0.f, 0.f, 0.f, 0.f};
        bf16x8 w0 = *(const bf16x8*)((const char*)Wbf + (ct*16+l15)*384 + 0  + kq*16);
        bf16x8 w1 = *(const bf16x8*)((const char*)Wbf + (ct*16+l15)*384 + 64 + kq*16);
        a = __builtin_amdgcn_mfma_f32_16x16x32_bf16(af0, w0, a, 0, 0, 0);
        a = __builtin_amdgcn_mfma_f32_16x16x32_bf16(af1, w1, a, 0, 0, 0);
        #pragma unroll
        for (int rg = 0; rg < 4; ++rg)
            if (rowo + rg < NATOM) Spre[(size_t)(rowo + rg) * 128 + ct * 16 + l15] = a[rg];
    }
}

// ---------- BN stats finalize (part layout: [blk][2*ncols] contiguous)
__global__ __launch_bounds__(256) void k_stats(const float* __restrict__ part,
                                               const float* __restrict__ scale,
                                               const float* __restrict__ offset,
                                               float* __restrict__ stats,
                                               int ncols, float invR) {
    int c = blockIdx.x, t = threadIdx.x;
    int stride = 2 * ncols;
    float s = 0.f, q = 0.f;
    for (int i = t; i < NBP; i += 256) {
        s += part[(size_t)i * stride + c];
        q += part[(size_t)i * stride + ncols + c];
    }
    __shared__ float rs[256], rq[256];
    rs[t] = s; rq[t] = q;
    __syncthreads();
    for (int o = 128; o > 0; o >>= 1) {
        if (t < o) { rs[t] += rs[t + o]; rq[t] += rq[t + o]; }
        __syncthreads();
    }
    if (t == 0) {
        float mean = rs[0] * invR;
        float var  = rq[0] * invR - mean * mean;
        float g = scale[c] * rsqrtf(var + EPS);
        stats[c] = g;
        stats[ncols + c] = offset[c] - mean * g;
    }
}

// ---------- fused GEMM pass over 96-row tiles (8 atoms), 8 waves, dbuf LDS.
template<int PASS>
__global__ __launch_bounds__(512, 4) void kpass(const int* __restrict__ idxg,
                                                const unsigned short* __restrict__ atombf,
                                                const unsigned short* __restrict__ bondbf,
                                                const unsigned short* __restrict__ Wbf,
                                                const float* __restrict__ Spre,
                                                const float* __restrict__ stats1,
                                                float* __restrict__ part,
                                                float* __restrict__ summed) {
    __shared__ __align__(16) unsigned char LB[2][LBSZ];
    __shared__ float sm[512];

    const int tid = threadIdx.x;
    const int wv  = tid >> 6;       // 0..7
    const int ln  = tid & 63;
    const int l15 = ln & 15;
    const int kq  = ln >> 4;
    const int rh  = wv >> 2;        // row half (0..1)
    const int cg  = wv & 3;         // col group (0..3)
    const int cf  = cg * 16 + l15;  // filter col (0..63)
    const int blk = blockIdx.x;

    const char* atomc = (const char*)atombf;
    const char* bondc = (const char*)bondbf;
    const char* sprec = (const char*)Spre;
    const char* idxc  = (const char*)idxg;

    sm[tid] = 0.f;
    // zero the 128-byte pad after the bond region in BOTH buffers (absorbs the
    // bond chunk-5 over-read at rowa=95 -> 0 * 0, never 0 * NaN)
    if (tid < 16) {
        f32x4 z4 = {0.f, 0.f, 0.f, 0.f};
        *(f32x4*)(&LB[tid >> 3][21504 + (tid & 7) * 16]) = z4;
    }

    // W fragments (k-chunks 2..5 : nbr + bond), held in registers
    bf16x8 wfr[2][4];
    #pragma unroll
    for (int h = 0; h < 2; ++h) {
        int col = cf + h * 64;
        #pragma unroll
        for (int j = 0; j < 4; ++j)
            wfr[h][j] = *(const bf16x8*)((const char*)Wbf + col * 384 + (j + 2) * 64 + kq * 16);
    }
    float gf = 0.f, hf = 0.f, gc = 0.f, hc = 0.f;
    if (PASS == 2) {
        gf = stats1[cf];       hf = stats1[128 + cf];
        gc = stats1[64 + cf];  hc = stats1[192 + cf];
    }
    float s0 = 0.f, q0 = 0.f, s1 = 0.f, q1 = 0.f;

    const int nbrlane = (((ln & 7) ^ (ln >> 3)) << 4);   // swizzled src offset within atom row
    const int r0row   = 8 * wv + (ln >> 3);              // idx row for my first nbr inst

    // stage panels(u) into buffer bb; also stage idx(u+NBP) into idx slot of bb
    auto STAGE = [&](int u, int bb, int iv0, int iv1) {
        unsigned char* buf = &LB[bb][0];
        if (wv < 4) {
            gload16(atomc + (size_t)iv0 * 128 + nbrlane, buf + wv * 1024 + ln * 16);
            gload16(atomc + (size_t)iv1 * 128 + nbrlane, buf + (wv + 8) * 1024 + ln * 16);
            gload16(bondc + (size_t)u * 9216 + (wv + 4) * 1024 + ln * 16,
                    buf + 12288 + (wv + 4) * 1024 + ln * 16);
            if (wv == 0)
                gload16(sprec + (size_t)u * 4096 + 3 * 1024 + ln * 16,
                        buf + 21632 + 3 * 1024 + ln * 16);
            if (wv == 1 && (u + NBP) < NT) {
                int B = min((u + NBP) * 384, IDXB - 1024);
                gload16(idxc + B + ln * 16, buf + 25728 + ln * 16);
            }
        } else {
            int w4 = wv - 4;
            gload16(atomc + (size_t)iv0 * 128 + nbrlane, buf + wv * 1024 + ln * 16);
            gload16(bondc + (size_t)u * 9216 + w4 * 1024 + ln * 16,
                    buf + 12288 + w4 * 1024 + ln * 16);
            if (wv == 4)
                gload16(bondc + (size_t)u * 9216 + 8 * 1024 + ln * 16,
                        buf + 12288 + 8 * 1024 + ln * 16);
            else
                gload16(sprec + (size_t)u * 4096 + (w4 - 1) * 1024 + ln * 16,
                        buf + 21632 + (w4 - 1) * 1024 + ln * 16);
        }
    };

    // ---- prologue: stage tile u0 (idx from global), plus idx(u0+NBP) into slot 0
    const int u0 = blk;
    {
        int iv0 = idxg[u0 * 96 + r0row];
        int iv1 = (wv < 4) ? idxg[u0 * 96 + 64 + r0row] : 0;
        STAGE(u0, 0, iv0, iv1);
    }

    int b = 0;
    for (int u = u0; u < NT; u += NBP) {
        asm volatile("s_waitcnt vmcnt(0) lgkmcnt(0)" ::: "memory");
        __builtin_amdgcn_s_barrier();                        // buffer b fully staged; b^1 free
        FENCE();
        if (u + NBP < NT) {
            int delta4 = max(0, (u + NBP) * 384 - (IDXB - 1024)) >> 2;
            const int* idxs = (const int*)(&LB[b][25728]);
            int iv0 = idxs[delta4 + r0row];
            int iv1 = (wv < 4) ? idxs[delta4 + 64 + r0row] : 0;
            STAGE(u + NBP, b ^ 1, iv0, iv1);
        }

        const unsigned char* buf = &LB[b][0];
        f32x4 z = {0.f, 0.f, 0.f, 0.f};
        f32x4 acc[2][3];
        #pragma unroll
        for (int s = 0; s < 3; ++s) { acc[0][s] = z; acc[1][s] = z; }

        #pragma unroll
        for (int sub = 0; sub < 3; ++sub) {
            int rowa = rh * 48 + sub * 16 + l15;
            #pragma unroll
            for (int j = 0; j < 4; ++j) {
                const unsigned char* p;
                if (j < 2)
                    p = buf + ((rowa * 128 + j * 64 + kq * 16) ^ ((rowa & 7) << 4));
                else
                    p = buf + 12288 + rowa * 96 + (j - 2) * 64 + kq * 16;
                bf16x8 a = *(const bf16x8*)p;
                acc[0][sub] = __builtin_amdgcn_mfma_f32_16x16x32_bf16(a, wfr[0][j], acc[0][sub], 0, 0, 0);
                acc[1][sub] = __builtin_amdgcn_mfma_f32_16x16x32_bf16(a, wfr[1][j], acc[1][sub], 0, 0, 0);
            }
        }

        const float* spref = (const float*)(&LB[b][21632]);
        if (PASS == 1) {
            #pragma unroll
            for (int sub = 0; sub < 3; ++sub) {
                int aL = (rh * 48 + sub * 16 + kq * 4) / 12;       // local atom 0..7
                float sp0 = spref[aL * 128 + cf];
                float sp1 = spref[aL * 128 + 64 + cf];
                #pragma unroll
                for (int rg = 0; rg < 4; ++rg) {
                    float v0 = acc[0][sub][rg] + sp0; s0 += v0; q0 = fmaf(v0, v0, q0);
                    float v1 = acc[1][sub][rg] + sp1; s1 += v1; q1 = fmaf(v1, v1, q1);
                }
            }
        } else {
            #pragma unroll
            for (int sub = 0; sub < 3; ++sub) {
                int aL = (rh * 48 + sub * 16 + kq * 4) / 12;
                float sp0 = spref[aL * 128 + cf];
                float sp1 = spref[aL * 128 + 64 + cf];
                float hf2 = fmaf(sp0, gf, hf);
                float hc2 = fmaf(sp1, gc, hc);
                float ps = 0.f;
                #pragma unroll
                for (int rg = 0; rg < 4; ++rg) {
                    float yf = fmaf(acc[0][sub][rg], gf, hf2);
                    float yc = fmaf(acc[1][sub][rg], gc, hc2);
                    float sig = __builtin_amdgcn_rcpf(1.f + __expf(-yf));
                    ps = fmaf(sig, softplus_f(yc), ps);
                }
                atomicAdd(&sm[aL * 64 + cf], ps);
            }
            asm volatile("s_waitcnt lgkmcnt(0)" ::: "memory");
            __builtin_amdgcn_s_barrier();                     // all m-sum atomics done
            FENCE();
            float v = sm[tid];
            sm[tid] = 0.f;
            summed[(size_t)u * 512 + tid] = v;
            s0 += v; q0 = fmaf(v, v, q0);
        }
        b ^= 1;
    }

    // ---- block-level partial stats, [blk][...] contiguous
    if (PASS == 1) {
        s0 += __shfl_xor(s0, 16); s0 += __shfl_xor(s0, 32);
        q0 += __shfl_xor(q0, 16); q0 += __shfl_xor(q0, 32);
        s1 += __shfl_xor(s1, 16); s1 += __shfl_xor(s1, 32);
        q1 += __shfl_xor(q1, 16); q1 += __shfl_xor(q1, 32);
        if (ln < 16) {
            atomicAdd(&sm[cf], s0);        atomicAdd(&sm[128 + cf], q0);
            atomicAdd(&sm[64 + cf], s1);   atomicAdd(&sm[192 + cf], q1);
        }
        __syncthreads();
        if (tid < 256) part[(size_t)blk * 256 + tid] = sm[tid];
    } else {
        __syncthreads();
        float* fs = (float*)(&LB[0][0]);
        fs[tid] = s0; fs[512 + tid] = q0;
        __syncthreads();
        if (tid < 64) {
            float S = 0.f, Q = 0.f;
            #pragma unroll
            for (int g = 0; g < 8; ++g) { S += fs[tid + 64 * g]; Q += fs[512 + tid + 64 * g]; }
            part[(size_t)blk * 128 + tid]      = S;
            part[(size_t)blk * 128 + 64 + tid] = Q;
        }
    }
}

// ---------- k5: out = softplus(atom + g2*summed + h2)
__global__ __launch_bounds__(256) void k5_out(const float* __restrict__ atom,
                                              const float* __restrict__ summed,
                                              const float* __restrict__ stats2,
                                              float* __restrict__ out) {
    int i4 = blockIdx.x * 256 + threadIdx.x;
    int base = i4 * 4;
    int c = base & 63;
    float4 av = *(const float4*)(atom + base);
    float4 sv = *(const float4*)(summed + base);
    float4 ov;
    ov.x = softplus_f(av.x + stats2[c + 0] * sv.x + stats2[64 + c + 0]);
    ov.y = softplus_f(av.y + stats2[c + 1] * sv.y + stats2[64 + c + 1]);
    ov.z = softplus_f(av.z + stats2[c + 2] * sv.z + stats2[64 + c + 2]);
    ov.w = softplus_f(av.w + stats2[c + 3] * sv.w + stats2[64 + c + 3]);
    *(float4*)(out + base) = ov;
}

extern "C" void kernel_launch(void* const* d_in, const int* in_sizes, int n_in,
                              void* d_out, int out_size, void* d_ws, size_t ws_size,
                              hipStream_t stream) {
    const int*   idx  = (const int*)  d_in[0];
    const float* atom = (const float*)d_in[1];
    const float* bond = (const float*)d_in[2];
    const float* W    = (const float*)d_in[3];
    // d_in[4] = bias: absorbed by BN1
    const float* bn1s = (const float*)d_in[5];
    const float* bn1o = (const float*)d_in[6];
    const float* bn2s = (const float*)d_in[7];
    const float* bn2o = (const float*)d_in[8];
    float* out = (float*)d_out;

    char* ws = (char*)d_ws;
    size_t off = 0;
    unsigned short* atombf = (unsigned short*)(ws + off); off += 12800000;       // [N][64]
    unsigned short* bondbf = (unsigned short*)(ws + off); off += 115201024;      // [RTOT][48] + slack
    unsigned short* Wbf    = (unsigned short*)(ws + off); off += 49152;          // [128][192]
    float* Spre   = (float*)(ws + off); off += (size_t)NATOM * 128 * 4;          // 51.2 MB
    float* part1  = (float*)(ws + off); off += (size_t)NBP * 256 * 4;
    float* stats1 = (float*)(ws + off); off += 1024;
    float* part2  = (float*)(ws + off); off += (size_t)NBP * 128 * 4;
    float* stats2 = (float*)(ws + off); off += 512;
    float* summed = (float*)(ws + off); off += (size_t)NATOM * 64 * 4;

    k0conv <<<12596, 256, 0, stream>>>(bond, atom, W, bondbf, atombf, Wbf);
    k0spre <<<1563, 256, 0, stream>>>(atombf, Wbf, Spre);
    kpass<1><<<NBP, 512, 0, stream>>>(idx, atombf, bondbf, Wbf, Spre, stats1, part1, summed);
    k_stats<<<128, 256, 0, stream>>>(part1, bn1s, bn1o, stats1, 128, 1.f / (float)RTOT);
    kpass<2><<<NBP, 512, 0, stream>>>(idx, atombf, bondbf, Wbf, Spre, stats1, part2, summed);
    k_stats<<<64, 256, 0, stream>>>(part2, bn2s, bn2o, stats2, 64, 1.f / (float)NATOM);
    k5_out <<<(NATOM * 64 / 4 + 255) / 256, 256, 0, stream>>>(atom, summed, stats2, out);
}